// Round 1
// baseline (1448.444 us; speedup 1.0000x reference)
//
#include <hip/hip_runtime.h>
#include <hip/hip_bf16.h>
#include <cstdint>
#include <cstddef>

// ---------------------------------------------------------------------------
// DeepseekMoE: x(1,2048,2048) fp32; gate_w(16,2048); w1(16,2816,2048);
// w2(16,2048,1408); shared_w1(5632,2048); shared_w2(2048,2816). Out fp32 T x H.
// Sparse top-6 grouped-GEMM formulation (numerically == dense-masked reference).
// ---------------------------------------------------------------------------

typedef __bf16 bf16;
typedef __bf16 bf16x8 __attribute__((ext_vector_type(8)));
typedef float  f32x4  __attribute__((ext_vector_type(4)));

constexpr int Hdim  = 2048;
constexpr int Idim  = 1408;
constexpr int NE    = 16;
constexpr int TOPK  = 6;
constexpr int ISdim = 2816;
constexpr int Ttok  = 2048;
// sum over experts of ceil(cnt_e/128)*128 <= 12288 + 16*127 = 14320
constexpr int MAX_SLOTS = 14336;

// async global->LDS, 16B per lane; LDS dst must be wave-uniform base + lane*16
__device__ __forceinline__ void gll16(const bf16* g, bf16* l) {
  __builtin_amdgcn_global_load_lds((__attribute__((address_space(1))) void*)(g),
                                   (__attribute__((address_space(3))) void*)(l),
                                   16, 0, 0);
}

// --------------------------- small kernels ---------------------------------

__global__ void init_kernel(int* cnt, int* fill, int* tok_of_slot, float* wt_of_slot) {
  int i = blockIdx.x * 256 + threadIdx.x;
  if (i < NE) { cnt[i] = 0; fill[i] = 0; }
  if (i < MAX_SLOTS) { tok_of_slot[i] = -1; wt_of_slot[i] = 0.f; }
}

__global__ void cvt_x_kernel(const float* __restrict__ x, bf16* __restrict__ xb) {
  int i = (blockIdx.x * 256 + threadIdx.x) * 8;
  f32x4 f0 = *(const f32x4*)(x + i);
  f32x4 f1 = *(const f32x4*)(x + i + 4);
  bf16x8 v;
#pragma unroll
  for (int j = 0; j < 4; j++) { v[j] = (bf16)f0[j]; v[j + 4] = (bf16)f1[j]; }
  *(bf16x8*)(xb + i) = v;
}

__global__ void router_kernel(const float* __restrict__ x, const float* __restrict__ gw,
                              int* __restrict__ sel_e, float* __restrict__ sel_w,
                              int* __restrict__ cnt) {
  int t = blockIdx.x;
  int lane = threadIdx.x;
  const float* xr = x + (size_t)t * Hdim;
  float acc[NE];
#pragma unroll
  for (int e = 0; e < NE; e++) acc[e] = 0.f;
  for (int h = lane; h < Hdim; h += 64) {
    float xv = xr[h];
#pragma unroll
    for (int e = 0; e < NE; e++) acc[e] += xv * gw[e * Hdim + h];
  }
#pragma unroll
  for (int e = 0; e < NE; e++) {
#pragma unroll
    for (int off = 32; off > 0; off >>= 1) acc[e] += __shfl_xor(acc[e], off, 64);
  }
  if (lane == 0) {
    float m = acc[0];
#pragma unroll
    for (int e = 1; e < NE; e++) m = fmaxf(m, acc[e]);
    float p[NE]; float s = 0.f;
#pragma unroll
    for (int e = 0; e < NE; e++) { p[e] = __expf(acc[e] - m); s += p[e]; }
    float inv = 1.f / s;
    bool used[NE];
#pragma unroll
    for (int e = 0; e < NE; e++) used[e] = false;
    for (int k = 0; k < TOPK; k++) {   // strict > keeps lowest index on ties (lax.top_k)
      int best = 0; float bv = -1.f;
      for (int e = 0; e < NE; e++) if (!used[e] && p[e] > bv) { bv = p[e]; best = e; }
      used[best] = true;
      sel_e[t * TOPK + k] = best;
      sel_w[t * TOPK + k] = bv * inv;   // NORM_TOPK_PROB=False -> raw softmax prob
      atomicAdd(&cnt[best], 1);
    }
  }
}

__global__ void scan_kernel(const int* __restrict__ cnt, int* __restrict__ pbase,
                            int* __restrict__ mtiles) {
  if (threadIdx.x == 0 && blockIdx.x == 0) {
    int pb = 0;
    for (int e = 0; e < NE; e++) {
      pbase[e] = pb;
      int mt = (cnt[e] + 127) >> 7;
      mtiles[e] = mt;
      pb += mt * 128;
    }
  }
}

__global__ void assign_kernel(const int* __restrict__ sel_e, const float* __restrict__ sel_w,
                              const int* __restrict__ pbase, int* __restrict__ fill,
                              int* __restrict__ tok_of_slot, float* __restrict__ wt_of_slot) {
  int i = blockIdx.x * 256 + threadIdx.x;
  if (i >= Ttok * TOPK) return;
  int t = i / TOPK;
  int e = sel_e[i];
  int pos = atomicAdd(&fill[e], 1);
  int slot = pbase[e] + pos;
  tok_of_slot[slot] = t;
  wt_of_slot[slot] = sel_w[i];
}

// --------------------------- gate+up fused GEMM -----------------------------
// act[row][col] = silu(A@G^T) * (A@U^T) * rowscale ; BM=128, BN=64, BK=32.
// A rows: GROUPED -> token-gathered from x_bf16 via tok_of_slot; else direct.
// Weights read fp32, converted to bf16 in regs during staging (pipelined 1 ahead).

template <bool GROUPED>
__global__ __launch_bounds__(256, 2)
void gateup_kernel(const bf16* __restrict__ Abase, const float* __restrict__ W,
                   bf16* __restrict__ Cact,
                   const int* __restrict__ tok_of_slot, const float* __restrict__ wt_of_slot,
                   const int* __restrict__ pbase, const int* __restrict__ mtiles,
                   int K, int Isz) {
  const int e = GROUPED ? blockIdx.z : 0;
  const int mt = blockIdx.y;
  if (GROUPED) { if (mt >= mtiles[e]) return; }
  const int row0 = (GROUPED ? pbase[e] : 0) + mt * 128;
  const int col0 = blockIdx.x * 64;
  const int tid = threadIdx.x;
  const int lane = tid & 63;
  const int wv = tid >> 6;
  const int wm = wv >> 1, wn = wv & 1;
  const int m16 = lane & 15, quad = lane >> 4;

  __shared__ __align__(16) bf16 ldsA[128 * 32];
  __shared__ __align__(16) bf16 ldsG[64 * 32];
  __shared__ __align__(16) bf16 ldsU[64 * 32];

  const int srow = tid >> 2;         // 0..63
  const int scol = (tid & 3) * 8;    // 0,8,16,24

  const bf16* aptr[2];
#pragma unroll
  for (int q = 0; q < 2; q++) {
    int r = row0 + q * 64 + srow;
    int tok = GROUPED ? tok_of_slot[r] : r;
    if (GROUPED && tok < 0) tok = 0;   // pad slot: rowscale==0 zeroes its act
    aptr[q] = Abase + (size_t)tok * K + scol;
  }
  const float* Wb = W + (size_t)e * 2 * Isz * K;
  const float* Grow = Wb + (size_t)(col0 + srow) * K + scol;
  const float* Urow = Wb + (size_t)(Isz + col0 + srow) * K + scol;

  f32x4 accg[4][2], accu[4][2];
#pragma unroll
  for (int i = 0; i < 4; i++)
#pragma unroll
    for (int j = 0; j < 2; j++)
#pragma unroll
      for (int r = 0; r < 4; r++) { accg[i][j][r] = 0.f; accu[i][j][r] = 0.f; }

  f32x4 gb0 = *(const f32x4*)(Grow);
  f32x4 gb1 = *(const f32x4*)(Grow + 4);
  f32x4 ub0 = *(const f32x4*)(Urow);
  f32x4 ub1 = *(const f32x4*)(Urow + 4);

  for (int k0 = 0; k0 < K; k0 += 32) {
    bf16x8 gv, uv;
#pragma unroll
    for (int j = 0; j < 4; j++) {
      gv[j] = (bf16)gb0[j]; gv[j + 4] = (bf16)gb1[j];
      uv[j] = (bf16)ub0[j]; uv[j + 4] = (bf16)ub1[j];
    }
    *(bf16x8*)(&ldsG[tid * 8]) = gv;
    *(bf16x8*)(&ldsU[tid * 8]) = uv;
#pragma unroll
    for (int q = 0; q < 2; q++) gll16(aptr[q] + k0, &ldsA[q * 2048 + tid * 8]);
    if (k0 + 32 < K) {   // prefetch next K-step's fp32 weights
      gb0 = *(const f32x4*)(Grow + k0 + 32);
      gb1 = *(const f32x4*)(Grow + k0 + 36);
      ub0 = *(const f32x4*)(Urow + k0 + 32);
      ub1 = *(const f32x4*)(Urow + k0 + 36);
    }
    __syncthreads();
    bf16x8 af[4], gf[2], uf[2];
#pragma unroll
    for (int i = 0; i < 4; i++)
      af[i] = *(const bf16x8*)(&ldsA[(wm * 64 + i * 16 + m16) * 32 + quad * 8]);
#pragma unroll
    for (int j = 0; j < 2; j++) {
      gf[j] = *(const bf16x8*)(&ldsG[(wn * 32 + j * 16 + m16) * 32 + quad * 8]);
      uf[j] = *(const bf16x8*)(&ldsU[(wn * 32 + j * 16 + m16) * 32 + quad * 8]);
    }
#pragma unroll
    for (int i = 0; i < 4; i++)
#pragma unroll
      for (int j = 0; j < 2; j++) {
        accg[i][j] = __builtin_amdgcn_mfma_f32_16x16x32_bf16(af[i], gf[j], accg[i][j], 0, 0, 0);
        accu[i][j] = __builtin_amdgcn_mfma_f32_16x16x32_bf16(af[i], uf[j], accu[i][j], 0, 0, 0);
      }
    __syncthreads();
  }

#pragma unroll
  for (int i = 0; i < 4; i++) {
#pragma unroll
    for (int r = 0; r < 4; r++) {
      int grow = row0 + wm * 64 + i * 16 + quad * 4 + r;
      float scale = 1.f;
      if (GROUPED) scale = wt_of_slot[grow];
#pragma unroll
      for (int j = 0; j < 2; j++) {
        float g = accg[i][j][r];
        float u = accu[i][j][r];
        float a = g * u * scale / (1.f + __expf(-g));   // silu(g)*u*scale
        Cact[(size_t)grow * Isz + (col0 + wn * 32 + j * 16 + m16)] = (bf16)a;
      }
    }
  }
}

// --------------------------- down-proj GEMM ---------------------------------
// BM=128, BN=128, BK=32. GROUPED: atomicAdd into out[token]; else plain store.

template <bool GROUPED>
__global__ __launch_bounds__(256, 2)
void down_kernel(const bf16* __restrict__ A, const float* __restrict__ W,
                 float* __restrict__ out, const int* __restrict__ tok_of_slot,
                 const int* __restrict__ pbase, const int* __restrict__ mtiles, int K) {
  const int e = GROUPED ? blockIdx.z : 0;
  const int mt = blockIdx.y;
  if (GROUPED) { if (mt >= mtiles[e]) return; }
  const int row0 = (GROUPED ? pbase[e] : 0) + mt * 128;
  const int col0 = blockIdx.x * 128;
  const int tid = threadIdx.x;
  const int lane = tid & 63;
  const int wv = tid >> 6;
  const int wm = wv >> 1, wn = wv & 1;
  const int m16 = lane & 15, quad = lane >> 4;

  __shared__ __align__(16) bf16 ldsA[128 * 32];
  __shared__ __align__(16) bf16 ldsB[128 * 32];

  const int srow = tid >> 2;
  const int scol = (tid & 3) * 8;

  const bf16* aptr[2];
#pragma unroll
  for (int q = 0; q < 2; q++)
    aptr[q] = A + (size_t)(row0 + q * 64 + srow) * K + scol;
  const float* Wb = W + (size_t)e * Hdim * K;
  const float* Brow[2];
#pragma unroll
  for (int q = 0; q < 2; q++)
    Brow[q] = Wb + (size_t)(col0 + q * 64 + srow) * K + scol;

  f32x4 acc[4][4];
#pragma unroll
  for (int i = 0; i < 4; i++)
#pragma unroll
    for (int j = 0; j < 4; j++)
#pragma unroll
      for (int r = 0; r < 4; r++) acc[i][j][r] = 0.f;

  f32x4 bb[2][2];
#pragma unroll
  for (int q = 0; q < 2; q++) {
    bb[q][0] = *(const f32x4*)(Brow[q]);
    bb[q][1] = *(const f32x4*)(Brow[q] + 4);
  }

  for (int k0 = 0; k0 < K; k0 += 32) {
#pragma unroll
    for (int q = 0; q < 2; q++) {
      bf16x8 bv;
#pragma unroll
      for (int j = 0; j < 4; j++) { bv[j] = (bf16)bb[q][0][j]; bv[j + 4] = (bf16)bb[q][1][j]; }
      *(bf16x8*)(&ldsB[q * 2048 + tid * 8]) = bv;
      gll16(aptr[q] + k0, &ldsA[q * 2048 + tid * 8]);
    }
    if (k0 + 32 < K) {
#pragma unroll
      for (int q = 0; q < 2; q++) {
        bb[q][0] = *(const f32x4*)(Brow[q] + k0 + 32);
        bb[q][1] = *(const f32x4*)(Brow[q] + k0 + 36);
      }
    }
    __syncthreads();
    bf16x8 af[4], bfr[4];
#pragma unroll
    for (int i = 0; i < 4; i++)
      af[i] = *(const bf16x8*)(&ldsA[(wm * 64 + i * 16 + m16) * 32 + quad * 8]);
#pragma unroll
    for (int j = 0; j < 4; j++)
      bfr[j] = *(const bf16x8*)(&ldsB[(wn * 64 + j * 16 + m16) * 32 + quad * 8]);
#pragma unroll
    for (int i = 0; i < 4; i++)
#pragma unroll
      for (int j = 0; j < 4; j++)
        acc[i][j] = __builtin_amdgcn_mfma_f32_16x16x32_bf16(af[i], bfr[j], acc[i][j], 0, 0, 0);
    __syncthreads();
  }

#pragma unroll
  for (int i = 0; i < 4; i++) {
#pragma unroll
    for (int r = 0; r < 4; r++) {
      int grow = row0 + wm * 64 + i * 16 + quad * 4 + r;
      int tok;
      if (GROUPED) {
        tok = tok_of_slot[grow];
        if (tok < 0) continue;   // padding slot
      } else {
        tok = grow;
      }
      float* orow = out + (size_t)tok * Hdim;
#pragma unroll
      for (int j = 0; j < 4; j++) {
        int col = col0 + wn * 64 + j * 16 + m16;
        if (GROUPED) atomicAdd(orow + col, acc[i][j][r]);
        else orow[col] = acc[i][j][r];
      }
    }
  }
}

// --------------------------- launch ----------------------------------------

extern "C" void kernel_launch(void* const* d_in, const int* in_sizes, int n_in,
                              void* d_out, int out_size, void* d_ws, size_t ws_size,
                              hipStream_t stream) {
  (void)in_sizes; (void)n_in; (void)out_size; (void)ws_size;
  const float* x   = (const float*)d_in[0];
  const float* gw  = (const float*)d_in[1];
  const float* w1  = (const float*)d_in[2];
  const float* w2  = (const float*)d_in[3];
  const float* sw1 = (const float*)d_in[4];
  const float* sw2 = (const float*)d_in[5];
  float* out = (float*)d_out;

  char* ws = (char*)d_ws;
  size_t off = 0;
  auto alloc = [&](size_t bytes) -> void* {
    void* p = ws + off;
    off += (bytes + 255) & ~(size_t)255;
    return p;
  };
  int*   cnt   = (int*)alloc(NE * 4);
  int*   fill  = (int*)alloc(NE * 4);
  int*   pbase = (int*)alloc(NE * 4);
  int*   mtl   = (int*)alloc(NE * 4);
  int*   sel_e = (int*)alloc((size_t)Ttok * TOPK * 4);
  float* sel_w = (float*)alloc((size_t)Ttok * TOPK * 4);
  int*   tok   = (int*)alloc((size_t)MAX_SLOTS * 4);
  float* wt    = (float*)alloc((size_t)MAX_SLOTS * 4);
  bf16*  xb    = (bf16*)alloc((size_t)Ttok * Hdim * 2);
  bf16*  actx  = (bf16*)alloc((size_t)MAX_SLOTS * Idim * 2);   // expert activations (slot rows)
  bf16*  acts  = (bf16*)alloc((size_t)Ttok * ISdim * 2);       // shared-expert activations
  // total ~61 MB

  init_kernel<<<(MAX_SLOTS + 255) / 256, 256, 0, stream>>>(cnt, fill, tok, wt);
  cvt_x_kernel<<<(Ttok * Hdim / 8 + 255) / 256, 256, 0, stream>>>(x, xb);
  router_kernel<<<Ttok, 64, 0, stream>>>(x, gw, sel_e, sel_w, cnt);
  scan_kernel<<<1, 64, 0, stream>>>(cnt, pbase, mtl);
  assign_kernel<<<(Ttok * TOPK + 255) / 256, 256, 0, stream>>>(sel_e, sel_w, pbase, fill, tok, wt);

  // expert gate+up (gathered A, silu*u*routing_weight epilogue)
  gateup_kernel<true><<<dim3(Idim / 64, 16, NE), 256, 0, stream>>>(
      xb, w1, actx, tok, wt, pbase, mtl, Hdim, Idim);
  // shared gate+up
  gateup_kernel<false><<<dim3(ISdim / 64, Ttok / 128, 1), 256, 0, stream>>>(
      xb, sw1, acts, nullptr, nullptr, nullptr, nullptr, Hdim, ISdim);
  // shared down: initializes d_out with plain stores (must precede atomics)
  down_kernel<false><<<dim3(Hdim / 128, Ttok / 128, 1), 256, 0, stream>>>(
      acts, sw2, out, nullptr, nullptr, nullptr, ISdim);
  // expert down: atomicAdd scatter into d_out
  down_kernel<true><<<dim3(Hdim / 128, 16, NE), 256, 0, stream>>>(
      actx, w2, out, tok, pbase, mtl, Idim);
}

// Round 2
// 1414.289 us; speedup vs baseline: 1.0242x; 1.0242x over previous
//
#include <hip/hip_runtime.h>
#include <hip/hip_bf16.h>
#include <cstdint>
#include <cstddef>

// ---------------------------------------------------------------------------
// DeepseekMoE: x(1,2048,2048) fp32; gate_w(16,2048); w1(16,2816,2048);
// w2(16,2048,1408); shared_w1(5632,2048); shared_w2(2048,2816). Out fp32 T x H.
// Sparse top-6 grouped-GEMM formulation. Round 2: bf16 weight pre-conversion
// (halves all weight traffic, w1b fits in L3) + BM=256 grouped tiles (halves
// the per-M-tile weight re-sweep factor).
// ---------------------------------------------------------------------------

typedef __bf16 bf16;
typedef __bf16 bf16x8 __attribute__((ext_vector_type(8)));
typedef float  f32x4  __attribute__((ext_vector_type(4)));

constexpr int Hdim  = 2048;
constexpr int Idim  = 1408;
constexpr int NE    = 16;
constexpr int TOPK  = 6;
constexpr int ISdim = 2816;
constexpr int Ttok  = 2048;
constexpr int BMG   = 256;            // grouped-kernel M tile
// sum over experts of ceil(cnt_e/256)*256 <= 12288 + 16*255 = 16368
constexpr int MAX_SLOTS = 16384;

__device__ __forceinline__ void gll16(const void* g, void* l) {
  __builtin_amdgcn_global_load_lds((__attribute__((address_space(1))) void*)(g),
                                   (__attribute__((address_space(3))) void*)(l),
                                   16, 0, 0);
}

// --------------------------- small kernels ---------------------------------

__global__ void init_kernel(int* cnt, int* fill, int* tok_of_slot, float* wt_of_slot) {
  int i = blockIdx.x * 256 + threadIdx.x;
  if (i < NE) { cnt[i] = 0; fill[i] = 0; }
  if (i < MAX_SLOTS) { tok_of_slot[i] = -1; wt_of_slot[i] = 0.f; }
}

// fp32 -> bf16, 8 elems/thread
__global__ void cvt_kernel(const float* __restrict__ src, bf16* __restrict__ dst, int n8) {
  int i = blockIdx.x * 256 + threadIdx.x;
  if (i >= n8) return;
  f32x4 f0 = *(const f32x4*)(src + (size_t)i * 8);
  f32x4 f1 = *(const f32x4*)(src + (size_t)i * 8 + 4);
  bf16x8 v;
#pragma unroll
  for (int j = 0; j < 4; j++) { v[j] = (bf16)f0[j]; v[j + 4] = (bf16)f1[j]; }
  *(bf16x8*)(dst + (size_t)i * 8) = v;
}

__global__ void router_kernel(const float* __restrict__ x, const float* __restrict__ gw,
                              int* __restrict__ sel_e, float* __restrict__ sel_w,
                              int* __restrict__ cnt) {
  int t = blockIdx.x;
  int lane = threadIdx.x;
  const float* xr = x + (size_t)t * Hdim;
  float acc[NE];
#pragma unroll
  for (int e = 0; e < NE; e++) acc[e] = 0.f;
  for (int h = lane; h < Hdim; h += 64) {
    float xv = xr[h];
#pragma unroll
    for (int e = 0; e < NE; e++) acc[e] += xv * gw[e * Hdim + h];
  }
#pragma unroll
  for (int e = 0; e < NE; e++) {
#pragma unroll
    for (int off = 32; off > 0; off >>= 1) acc[e] += __shfl_xor(acc[e], off, 64);
  }
  if (lane == 0) {
    float m = acc[0];
#pragma unroll
    for (int e = 1; e < NE; e++) m = fmaxf(m, acc[e]);
    float p[NE]; float s = 0.f;
#pragma unroll
    for (int e = 0; e < NE; e++) { p[e] = __expf(acc[e] - m); s += p[e]; }
    float inv = 1.f / s;
    bool used[NE];
#pragma unroll
    for (int e = 0; e < NE; e++) used[e] = false;
    for (int k = 0; k < TOPK; k++) {   // strict > keeps lowest index on ties (lax.top_k)
      int best = 0; float bv = -1.f;
      for (int e = 0; e < NE; e++) if (!used[e] && p[e] > bv) { bv = p[e]; best = e; }
      used[best] = true;
      sel_e[t * TOPK + k] = best;
      sel_w[t * TOPK + k] = bv * inv;   // NORM_TOPK_PROB=False -> raw softmax prob
      atomicAdd(&cnt[best], 1);
    }
  }
}

__global__ void scan_kernel(const int* __restrict__ cnt, int* __restrict__ pbase,
                            int* __restrict__ mtiles) {
  if (threadIdx.x == 0 && blockIdx.x == 0) {
    int pb = 0;
    for (int e = 0; e < NE; e++) {
      pbase[e] = pb;
      int mt = (cnt[e] + BMG - 1) / BMG;
      mtiles[e] = mt;
      pb += mt * BMG;
    }
  }
}

__global__ void assign_kernel(const int* __restrict__ sel_e, const float* __restrict__ sel_w,
                              const int* __restrict__ pbase, int* __restrict__ fill,
                              int* __restrict__ tok_of_slot, float* __restrict__ wt_of_slot) {
  int i = blockIdx.x * 256 + threadIdx.x;
  if (i >= Ttok * TOPK) return;
  int t = i / TOPK;
  int e = sel_e[i];
  int pos = atomicAdd(&fill[e], 1);
  int slot = pbase[e] + pos;
  tok_of_slot[slot] = t;
  wt_of_slot[slot] = sel_w[i];
}

// --------------------------- gate+up fused GEMM -----------------------------
// act[row][col] = silu(A@G^T) * (A@U^T) * rowscale.  BN=64, BK=32, BM template.
// 4 row-waves: wave w computes rows [w*BM/4, (w+1)*BM/4) x all 64 cols.
// BF16B: B staged via global_load_lds from pre-converted bf16 weights.
// else : B read fp32, converted in regs (pipelined one K-step ahead).

template <bool GROUPED, bool BF16B, int BM>
__global__ __launch_bounds__(256, 2)
void gateup_kernel(const bf16* __restrict__ Abase, const void* __restrict__ Wv,
                   bf16* __restrict__ Cact,
                   const int* __restrict__ tok_of_slot, const float* __restrict__ wt_of_slot,
                   const int* __restrict__ pbase, const int* __restrict__ mtiles,
                   int K, int Isz) {
  constexpr int NQ = BM / 64;        // 64-row staging chunks of A
  constexpr int WROWS = BM / 4;      // rows per wave
  constexpr int NI = WROWS / 16;     // 16-row MFMA fragments per wave
  const int e = GROUPED ? blockIdx.z : 0;
  const int mt = blockIdx.y;
  if (GROUPED) { if (mt >= mtiles[e]) return; }
  const int row0 = (GROUPED ? pbase[e] : 0) + mt * BM;
  const int col0 = blockIdx.x * 64;
  const int tid = threadIdx.x;
  const int lane = tid & 63;
  const int wv = tid >> 6;
  const int m16 = lane & 15, quad = lane >> 4;

  __shared__ __align__(16) bf16 ldsA[BM * 32];
  __shared__ __align__(16) bf16 ldsG[64 * 32];
  __shared__ __align__(16) bf16 ldsU[64 * 32];

  const int srow = tid >> 2;         // 0..63
  const int scol = (tid & 3) * 8;    // 0,8,16,24

  const bf16* aptr[NQ];
#pragma unroll
  for (int q = 0; q < NQ; q++) {
    int r = row0 + q * 64 + srow;
    int tok = GROUPED ? tok_of_slot[r] : r;
    if (GROUPED && tok < 0) tok = 0;   // pad slot: rowscale==0 zeroes its act
    aptr[q] = Abase + (size_t)tok * K + scol;
  }

  const bf16* gptrB = nullptr; const bf16* uptrB = nullptr;
  const float* GrowF = nullptr; const float* UrowF = nullptr;
  f32x4 gb0, gb1, ub0, ub1;
  if constexpr (BF16B) {
    const bf16* Wb = (const bf16*)Wv + (size_t)e * 2 * Isz * K;
    gptrB = Wb + (size_t)(col0 + srow) * K + scol;
    uptrB = Wb + (size_t)(Isz + col0 + srow) * K + scol;
  } else {
    const float* Wb = (const float*)Wv + (size_t)e * 2 * Isz * K;
    GrowF = Wb + (size_t)(col0 + srow) * K + scol;
    UrowF = Wb + (size_t)(Isz + col0 + srow) * K + scol;
    gb0 = *(const f32x4*)(GrowF);
    gb1 = *(const f32x4*)(GrowF + 4);
    ub0 = *(const f32x4*)(UrowF);
    ub1 = *(const f32x4*)(UrowF + 4);
  }

  f32x4 accg[NI][4], accu[NI][4];
#pragma unroll
  for (int i = 0; i < NI; i++)
#pragma unroll
    for (int j = 0; j < 4; j++)
#pragma unroll
      for (int r = 0; r < 4; r++) { accg[i][j][r] = 0.f; accu[i][j][r] = 0.f; }

  for (int k0 = 0; k0 < K; k0 += 32) {
    if constexpr (BF16B) {
      gll16(gptrB + k0, &ldsG[tid * 8]);
      gll16(uptrB + k0, &ldsU[tid * 8]);
    } else {
      bf16x8 gv, uv;
#pragma unroll
      for (int j = 0; j < 4; j++) {
        gv[j] = (bf16)gb0[j]; gv[j + 4] = (bf16)gb1[j];
        uv[j] = (bf16)ub0[j]; uv[j + 4] = (bf16)ub1[j];
      }
      *(bf16x8*)(&ldsG[tid * 8]) = gv;
      *(bf16x8*)(&ldsU[tid * 8]) = uv;
      if (k0 + 32 < K) {   // prefetch next K-step's fp32 weights
        gb0 = *(const f32x4*)(GrowF + k0 + 32);
        gb1 = *(const f32x4*)(GrowF + k0 + 36);
        ub0 = *(const f32x4*)(UrowF + k0 + 32);
        ub1 = *(const f32x4*)(UrowF + k0 + 36);
      }
    }
#pragma unroll
    for (int q = 0; q < NQ; q++) gll16(aptr[q] + k0, &ldsA[q * 2048 + tid * 8]);
    __syncthreads();
    bf16x8 af[NI], gf[4], uf[4];
#pragma unroll
    for (int i = 0; i < NI; i++)
      af[i] = *(const bf16x8*)(&ldsA[(wv * WROWS + i * 16 + m16) * 32 + quad * 8]);
#pragma unroll
    for (int j = 0; j < 4; j++) {
      gf[j] = *(const bf16x8*)(&ldsG[(j * 16 + m16) * 32 + quad * 8]);
      uf[j] = *(const bf16x8*)(&ldsU[(j * 16 + m16) * 32 + quad * 8]);
    }
#pragma unroll
    for (int i = 0; i < NI; i++)
#pragma unroll
      for (int j = 0; j < 4; j++) {
        accg[i][j] = __builtin_amdgcn_mfma_f32_16x16x32_bf16(af[i], gf[j], accg[i][j], 0, 0, 0);
        accu[i][j] = __builtin_amdgcn_mfma_f32_16x16x32_bf16(af[i], uf[j], accu[i][j], 0, 0, 0);
      }
    __syncthreads();
  }

#pragma unroll
  for (int i = 0; i < NI; i++) {
#pragma unroll
    for (int r = 0; r < 4; r++) {
      int grow = row0 + wv * WROWS + i * 16 + quad * 4 + r;
      float scale = 1.f;
      if (GROUPED) scale = wt_of_slot[grow];
#pragma unroll
      for (int j = 0; j < 4; j++) {
        float g = accg[i][j][r];
        float u = accu[i][j][r];
        float a = g * u * scale / (1.f + __expf(-g));   // silu(g)*u*scale
        Cact[(size_t)grow * Isz + (col0 + j * 16 + m16)] = (bf16)a;
      }
    }
  }
}

// --------------------------- down-proj GEMM ---------------------------------
// BN=128, BK=32, BM template; 4 row-waves x 128 cols each.
// GROUPED: atomicAdd scatter into out[token]; else plain store (init).

template <bool GROUPED, bool BF16B, int BM>
__global__ __launch_bounds__(256, 2)
void down_kernel(const bf16* __restrict__ A, const void* __restrict__ Wv,
                 float* __restrict__ out, const int* __restrict__ tok_of_slot,
                 const int* __restrict__ pbase, const int* __restrict__ mtiles, int K) {
  constexpr int NQ = BM / 64;
  constexpr int WROWS = BM / 4;
  constexpr int NI = WROWS / 16;
  const int e = GROUPED ? blockIdx.z : 0;
  const int mt = blockIdx.y;
  if (GROUPED) { if (mt >= mtiles[e]) return; }
  const int row0 = (GROUPED ? pbase[e] : 0) + mt * BM;
  const int col0 = blockIdx.x * 128;
  const int tid = threadIdx.x;
  const int lane = tid & 63;
  const int wv = tid >> 6;
  const int m16 = lane & 15, quad = lane >> 4;

  __shared__ __align__(16) bf16 ldsA[BM * 32];
  __shared__ __align__(16) bf16 ldsB[128 * 32];

  const int srow = tid >> 2;
  const int scol = (tid & 3) * 8;

  const bf16* aptr[NQ];
#pragma unroll
  for (int q = 0; q < NQ; q++)
    aptr[q] = A + (size_t)(row0 + q * 64 + srow) * K + scol;

  const bf16* bptrB[2] = {nullptr, nullptr};
  const float* BrowF[2] = {nullptr, nullptr};
  f32x4 bb[2][2];
  if constexpr (BF16B) {
    const bf16* Wb = (const bf16*)Wv + (size_t)e * Hdim * K;
#pragma unroll
    for (int q = 0; q < 2; q++)
      bptrB[q] = Wb + (size_t)(col0 + q * 64 + srow) * K + scol;
  } else {
    const float* Wb = (const float*)Wv + (size_t)e * Hdim * K;
#pragma unroll
    for (int q = 0; q < 2; q++) {
      BrowF[q] = Wb + (size_t)(col0 + q * 64 + srow) * K + scol;
      bb[q][0] = *(const f32x4*)(BrowF[q]);
      bb[q][1] = *(const f32x4*)(BrowF[q] + 4);
    }
  }

  f32x4 acc[NI][8];
#pragma unroll
  for (int i = 0; i < NI; i++)
#pragma unroll
    for (int j = 0; j < 8; j++)
#pragma unroll
      for (int r = 0; r < 4; r++) acc[i][j][r] = 0.f;

  for (int k0 = 0; k0 < K; k0 += 32) {
    if constexpr (BF16B) {
#pragma unroll
      for (int q = 0; q < 2; q++) gll16(bptrB[q] + k0, &ldsB[q * 2048 + tid * 8]);
    } else {
#pragma unroll
      for (int q = 0; q < 2; q++) {
        bf16x8 bv;
#pragma unroll
        for (int j = 0; j < 4; j++) { bv[j] = (bf16)bb[q][0][j]; bv[j + 4] = (bf16)bb[q][1][j]; }
        *(bf16x8*)(&ldsB[q * 2048 + tid * 8]) = bv;
      }
      if (k0 + 32 < K) {
#pragma unroll
        for (int q = 0; q < 2; q++) {
          bb[q][0] = *(const f32x4*)(BrowF[q] + k0 + 32);
          bb[q][1] = *(const f32x4*)(BrowF[q] + k0 + 36);
        }
      }
    }
#pragma unroll
    for (int q = 0; q < NQ; q++) gll16(aptr[q] + k0, &ldsA[q * 2048 + tid * 8]);
    __syncthreads();
    bf16x8 af[NI], bfr[8];
#pragma unroll
    for (int i = 0; i < NI; i++)
      af[i] = *(const bf16x8*)(&ldsA[(wv * WROWS + i * 16 + m16) * 32 + quad * 8]);
#pragma unroll
    for (int j = 0; j < 8; j++)
      bfr[j] = *(const bf16x8*)(&ldsB[(j * 16 + m16) * 32 + quad * 8]);
#pragma unroll
    for (int i = 0; i < NI; i++)
#pragma unroll
      for (int j = 0; j < 8; j++)
        acc[i][j] = __builtin_amdgcn_mfma_f32_16x16x32_bf16(af[i], bfr[j], acc[i][j], 0, 0, 0);
    __syncthreads();
  }

#pragma unroll
  for (int i = 0; i < NI; i++) {
#pragma unroll
    for (int r = 0; r < 4; r++) {
      int grow = row0 + wv * WROWS + i * 16 + quad * 4 + r;
      int tok;
      if (GROUPED) {
        tok = tok_of_slot[grow];
        if (tok < 0) continue;   // padding slot
      } else {
        tok = grow;
      }
      float* orow = out + (size_t)tok * Hdim;
#pragma unroll
      for (int j = 0; j < 8; j++) {
        int col = col0 + j * 16 + m16;
        if (GROUPED) atomicAdd(orow + col, acc[i][j][r]);
        else orow[col] = acc[i][j][r];
      }
    }
  }
}

// --------------------------- launch ----------------------------------------

extern "C" void kernel_launch(void* const* d_in, const int* in_sizes, int n_in,
                              void* d_out, int out_size, void* d_ws, size_t ws_size,
                              hipStream_t stream) {
  (void)in_sizes; (void)n_in; (void)out_size;
  const float* x   = (const float*)d_in[0];
  const float* gw  = (const float*)d_in[1];
  const float* w1  = (const float*)d_in[2];
  const float* w2  = (const float*)d_in[3];
  const float* sw1 = (const float*)d_in[4];
  const float* sw2 = (const float*)d_in[5];
  float* out = (float*)d_out;

  char* ws = (char*)d_ws;
  size_t off = 0;
  auto alloc = [&](size_t bytes) -> void* {
    void* p = ws + off;
    off += (bytes + 255) & ~(size_t)255;
    return p;
  };
  int*   cnt   = (int*)alloc(NE * 4);
  int*   fill  = (int*)alloc(NE * 4);
  int*   pbase = (int*)alloc(NE * 4);
  int*   mtl   = (int*)alloc(NE * 4);
  int*   sel_e = (int*)alloc((size_t)Ttok * TOPK * 4);
  float* sel_w = (float*)alloc((size_t)Ttok * TOPK * 4);
  int*   tok   = (int*)alloc((size_t)MAX_SLOTS * 4);
  float* wt    = (float*)alloc((size_t)MAX_SLOTS * 4);
  bf16*  xb    = (bf16*)alloc((size_t)Ttok * Hdim * 2);
  bf16*  actx  = (bf16*)alloc((size_t)MAX_SLOTS * Idim * 2);   // expert activations
  bf16*  acts  = (bf16*)alloc((size_t)Ttok * ISdim * 2);       // shared activations

  const size_t n_w1  = (size_t)NE * 2 * Idim * Hdim;   // 92.3M
  const size_t n_w2  = (size_t)NE * Hdim * Idim;       // 46.1M
  const size_t n_sw1 = (size_t)2 * ISdim * Hdim;       // 11.5M
  const size_t n_sw2 = (size_t)Hdim * ISdim;           // 5.8M
  size_t off_base = off;
  bf16* w1b  = (bf16*)alloc(n_w1 * 2);
  bf16* w2b  = (bf16*)alloc(n_w2 * 2);
  bf16* sw1b = (bf16*)alloc(n_sw1 * 2);
  bf16* sw2b = (bf16*)alloc(n_sw2 * 2);
  const bool use_bf16w = (off <= ws_size);   // ~378 MB total; ws_size is fixed
  (void)off_base;

  init_kernel<<<(MAX_SLOTS + 255) / 256, 256, 0, stream>>>(cnt, fill, tok, wt);
  cvt_kernel<<<((int)(Ttok * (size_t)Hdim / 8) + 255) / 256, 256, 0, stream>>>(x, xb, Ttok * Hdim / 8);
  router_kernel<<<Ttok, 64, 0, stream>>>(x, gw, sel_e, sel_w, cnt);
  scan_kernel<<<1, 64, 0, stream>>>(cnt, pbase, mtl);
  assign_kernel<<<(Ttok * TOPK + 255) / 256, 256, 0, stream>>>(sel_e, sel_w, pbase, fill, tok, wt);

  if (use_bf16w) {
    cvt_kernel<<<((int)(n_w1 / 8) + 255) / 256, 256, 0, stream>>>(w1, w1b, (int)(n_w1 / 8));
    cvt_kernel<<<((int)(n_w2 / 8) + 255) / 256, 256, 0, stream>>>(w2, w2b, (int)(n_w2 / 8));
    cvt_kernel<<<((int)(n_sw1 / 8) + 255) / 256, 256, 0, stream>>>(sw1, sw1b, (int)(n_sw1 / 8));
    cvt_kernel<<<((int)(n_sw2 / 8) + 255) / 256, 256, 0, stream>>>(sw2, sw2b, (int)(n_sw2 / 8));

    gateup_kernel<true, true, BMG><<<dim3(Idim / 64, Ttok / BMG, NE), 256, 0, stream>>>(
        xb, w1b, actx, tok, wt, pbase, mtl, Hdim, Idim);
    gateup_kernel<false, true, 128><<<dim3(ISdim / 64, Ttok / 128, 1), 256, 0, stream>>>(
        xb, sw1b, acts, nullptr, nullptr, nullptr, nullptr, Hdim, ISdim);
    down_kernel<false, true, 128><<<dim3(Hdim / 128, Ttok / 128, 1), 256, 0, stream>>>(
        acts, sw2b, out, nullptr, nullptr, nullptr, ISdim);
    down_kernel<true, true, BMG><<<dim3(Hdim / 128, Ttok / BMG, NE), 256, 0, stream>>>(
        actx, w2b, out, tok, pbase, mtl, Idim);
  } else {
    gateup_kernel<true, false, BMG><<<dim3(Idim / 64, Ttok / BMG, NE), 256, 0, stream>>>(
        xb, w1, actx, tok, wt, pbase, mtl, Hdim, Idim);
    gateup_kernel<false, false, 128><<<dim3(ISdim / 64, Ttok / 128, 1), 256, 0, stream>>>(
        xb, sw1, acts, nullptr, nullptr, nullptr, nullptr, Hdim, ISdim);
    down_kernel<false, false, 128><<<dim3(Hdim / 128, Ttok / 128, 1), 256, 0, stream>>>(
        acts, sw2, out, nullptr, nullptr, nullptr, ISdim);
    down_kernel<true, false, BMG><<<dim3(Hdim / 128, Ttok / BMG, NE), 256, 0, stream>>>(
        actx, w2, out, tok, pbase, mtl, Idim);
  }
}